// Round 4
// baseline (1238.325 us; speedup 1.0000x reference)
//
#include <hip/hip_runtime.h>

typedef float v2 __attribute__((ext_vector_type(2)));

// Fold 1/sqrt(3) (and log2(e) when raw exp2 is available) into staged Wq/bq.
#if __has_builtin(__builtin_amdgcn_exp2f)
#define QSCALE 0.8329441541679836f   // (1/sqrt(3)) * log2(e)
#define EXPFN(v) __builtin_amdgcn_exp2f(v)
#else
#define QSCALE 0.57735026918962576f  // 1/sqrt(3)
#define EXPFN(v) __expf(v)
#endif

// LDS layout, float offsets.
// Q/K/V: [5 segs][3 pairs][16 floats]; seg stride 56. Pair p holds
// head-interleaved rows (p, p+3):
//   [ (W[p][0],W[p+3][0]) ... (W[p][5],W[p+3][5]) (b[p],b[p+3]) pad pad ]
// Wo: [3 pairs][16], pair p = spatial rows (2p, 2p+1), bias in slot 12.
#define OFF_WQ 0
#define OFF_WK 280
#define OFF_WV 560
#define OFF_WO 840
#define LDS_FLOATS 888

template<int N>
__device__ __forceinline__ float rr(float x) {
    // row_ror within each 16-lane row: lane i <- lane (i+N)&15
    return __int_as_float(__builtin_amdgcn_mov_dpp(__float_as_int(x), 0x120 + N, 0xF, 0xF, true));
}
template<int N>
__device__ __forceinline__ v2 ror2(v2 a) { v2 r; r.x = rr<N>(a.x); r.y = rr<N>(a.y); return r; }
__device__ __forceinline__ v2 fma2(v2 a, v2 b, v2 c) { return __builtin_elementwise_fma(a, b, c); }
__device__ __forceinline__ v2 splat(float x) { v2 r; r.x = x; r.y = x; return r; }

__global__ __launch_bounds__(256, 8) void attn_seg_kernel(
    const float* __restrict__ x,
    const float* __restrict__ Wq, const float* __restrict__ bq,
    const float* __restrict__ Wk, const float* __restrict__ bk,
    const float* __restrict__ Wv, const float* __restrict__ bv,
    const float* __restrict__ Wo, const float* __restrict__ bo,
    float* __restrict__ out, int total)
{
    __shared__ __align__(16) float lds[LDS_FLOATS];
    const int t = threadIdx.x;

    // ---- stage weights (one-time) ----
    if (t < 180) {
        int sg = t / 36, rm = t - sg * 36, o = rm / 6, d = rm - o * 6;
        int dst = sg * 56 + (o % 3) * 16 + d * 2 + (o / 3);
        lds[OFF_WQ + dst] = Wq[t] * QSCALE;
        lds[OFF_WK + dst] = Wk[t];
        lds[OFF_WV + dst] = Wv[t];
    }
    if (t < 30) {
        int sg = t / 6, o = t - sg * 6;
        int dst = sg * 56 + (o % 3) * 16 + 12 + (o / 3);
        lds[OFF_WQ + dst] = bq[t] * QSCALE;
        lds[OFF_WK + dst] = bk[t];
        lds[OFF_WV + dst] = bv[t];
    }
    if (t < 36) {
        int o = t / 6, d = t - o * 6;
        lds[OFF_WO + (o >> 1) * 16 + d * 2 + (o & 1)] = Wo[t];
    }
    if (t < 6) {
        lds[OFF_WO + (t >> 1) * 16 + 12 + (t & 1)] = bo[t];
    }

    const int s = t & 15;   // sequence position within batch element
    // SEG = [0, 1*5, 2*3, 3, 4*6]
    const int seg = (s == 0) ? 0 : (s < 6) ? 1 : (s < 9) ? 2 : (s == 9) ? 3 : 4;

    const int pos = blockIdx.x * 256 + t;   // global flat (b*16+s)
    const bool valid = pos < total;
    float x0=0.f,x1=0.f,x2=0.f,x3=0.f,x4=0.f,x5=0.f;
    if (valid) {
        const float* xp = x + (size_t)pos * 6;
        float2 a = *(const float2*)xp, b = *(const float2*)(xp + 2), c = *(const float2*)(xp + 4);
        x0=a.x; x1=a.y; x2=b.x; x3=b.y; x4=c.x; x5=c.y;
    }

    __syncthreads();   // weights visible

    // ---- projections: head-interleaved pairs, bias folded into row ----
    v2 q[3], k[3], v[3];

#define PROJ(OFF, DST) { \
    const float* Wb = &lds[(OFF) + seg * 56]; \
    _Pragma("unroll") \
    for (int p = 0; p < 3; p++) { \
        float4 wa = *(const float4*)(Wb + p * 16); \
        float4 wm = *(const float4*)(Wb + p * 16 + 4); \
        float4 wc = *(const float4*)(Wb + p * 16 + 8); \
        float2 bb = *(const float2*)(Wb + p * 16 + 12); \
        v2 w0; w0.x=wa.x; w0.y=wa.y;  v2 w1; w1.x=wa.z; w1.y=wa.w; \
        v2 w2; w2.x=wm.x; w2.y=wm.y;  v2 w3; w3.x=wm.z; w3.y=wm.w; \
        v2 w4; w4.x=wc.x; w4.y=wc.y;  v2 w5; w5.x=wc.z; w5.y=wc.w; \
        v2 acc; acc.x = bb.x; acc.y = bb.y; \
        acc = fma2(w0, splat(x0), acc); acc = fma2(w1, splat(x1), acc); \
        acc = fma2(w2, splat(x2), acc); acc = fma2(w3, splat(x3), acc); \
        acc = fma2(w4, splat(x4), acc); acc = fma2(w5, splat(x5), acc); \
        DST[p] = acc; \
    } }

    PROJ(OFF_WQ, q)
    PROJ(OFF_WK, k)
    PROJ(OFF_WV, v)
#undef PROJ

    // ---- fused score -> exp -> sum -> PV, DPP row-rotate, online (no max) ----
    v2 sum, c0, c1, c2;
    {
        v2 sc = fma2(q[0], k[0], fma2(q[1], k[1], q[2] * k[2]));
        v2 pr; pr.x = EXPFN(sc.x); pr.y = EXPFN(sc.y);
        sum = pr; c0 = pr * v[0]; c1 = pr * v[1]; c2 = pr * v[2];
    }

#define STEP(J) { \
    v2 a0 = ror2<J>(k[0]), a1 = ror2<J>(k[1]), a2 = ror2<J>(k[2]); \
    v2 sc = fma2(q[0], a0, fma2(q[1], a1, q[2] * a2)); \
    v2 pr; pr.x = EXPFN(sc.x); pr.y = EXPFN(sc.y); \
    sum += pr; \
    v2 b0 = ror2<J>(v[0]), b1 = ror2<J>(v[1]), b2 = ror2<J>(v[2]); \
    c0 = fma2(pr, b0, c0); c1 = fma2(pr, b1, c1); c2 = fma2(pr, b2, c2); }

    STEP(1)  STEP(2)  STEP(3)  STEP(4)  STEP(5)
    STEP(6)  STEP(7)  STEP(8)  STEP(9)  STEP(10)
    STEP(11) STEP(12) STEP(13) STEP(14) STEP(15)
#undef STEP

    // ---- normalize: pair = (1/sum_h0, 1/sum_h1) ----
    v2 inv; inv.x = __builtin_amdgcn_rcpf(sum.x); inv.y = __builtin_amdgcn_rcpf(sum.y);
    c0 *= inv; c1 *= inv; c2 *= inv;
    const float ctx[6] = {c0.x, c1.x, c2.x, c0.y, c1.y, c2.y};

    // ---- output projection (pairs over spatial rows) + store ----
    float* op = out + (size_t)pos * 6;
    const float* Wb = &lds[OFF_WO];
    #pragma unroll
    for (int p = 0; p < 3; p++) {
        float4 wa = *(const float4*)(Wb + p * 16);
        float4 wm = *(const float4*)(Wb + p * 16 + 4);
        float4 wc = *(const float4*)(Wb + p * 16 + 8);
        float2 bb = *(const float2*)(Wb + p * 16 + 12);
        v2 w0; w0.x=wa.x; w0.y=wa.y;  v2 w1; w1.x=wa.z; w1.y=wa.w;
        v2 w2; w2.x=wm.x; w2.y=wm.y;  v2 w3; w3.x=wm.z; w3.y=wm.w;
        v2 w4; w4.x=wc.x; w4.y=wc.y;  v2 w5; w5.x=wc.z; w5.y=wc.w;
        v2 acc; acc.x = bb.x; acc.y = bb.y;
        acc = fma2(w0, splat(ctx[0]), acc); acc = fma2(w1, splat(ctx[1]), acc);
        acc = fma2(w2, splat(ctx[2]), acc); acc = fma2(w3, splat(ctx[3]), acc);
        acc = fma2(w4, splat(ctx[4]), acc); acc = fma2(w5, splat(ctx[5]), acc);
        if (valid) *(float2*)(op + 2 * p) = make_float2(acc.x, acc.y);
    }
}

extern "C" void kernel_launch(void* const* d_in, const int* in_sizes, int n_in,
                              void* d_out, int out_size, void* d_ws, size_t ws_size,
                              hipStream_t stream) {
    const float* x  = (const float*)d_in[0];
    const float* Wq = (const float*)d_in[1];
    const float* bq = (const float*)d_in[2];
    const float* Wk = (const float*)d_in[3];
    const float* bk = (const float*)d_in[4];
    const float* Wv = (const float*)d_in[5];
    const float* bv = (const float*)d_in[6];
    const float* Wo = (const float*)d_in[7];
    const float* bo = (const float*)d_in[8];
    float* out = (float*)d_out;

    const int total = in_sizes[0] / 6;        // B*16 positions
    const int grid  = (total + 255) / 256;    // 16 batch elems / block
    attn_seg_kernel<<<grid, 256, 0, stream>>>(x, Wq, bq, Wk, bk, Wv, bv, Wo, bo, out, total);
}